// Round 3
// baseline (295.661 us; speedup 1.0000x reference)
//
#include <hip/hip_runtime.h>
#include <hip/hip_cooperative_groups.h>
#include <math.h>

namespace cg = cooperative_groups;

#define BB 32
#define HH 56
#define WW 56
#define CC 256
#define NPIX (BB * HH * WW)     // 100352 pixels; CC=256 floats per pixel
#define NTASK (NPIX / 4)        // 25088 wave-tasks, 4 pixels each
#define NBLK  1024              // 4 blocks/CU x 256 CUs -> all co-resident
#define NWAVE (NBLK * 4)        // 4096 waves; each does 6-7 tasks per phase

// Single cooperative kernel:
//   phase 1: per-pixel channel mean+max (4 pixels/wave, grid-stride)
//   grid.sync()
//   phase 2: 7x7 'SAME' conv (2->1) + bias + sigmoid + broadcast scale
// Merging removes one launch boundary/ramp and keeps weights resident.
__global__ __launch_bounds__(256, 4) void fused_all(
    const float* __restrict__ x, const float* __restrict__ cw,
    const float* __restrict__ cb, float* __restrict__ out,
    float* __restrict__ pooled)
{
    int lane  = threadIdx.x & 63;
    int wave0 = blockIdx.x * 4 + (threadIdx.x >> 6);
    const float4* x4 = (const float4*)x;

    // ---- Phase 1: pool (mean + max over 256 channels) ----
    for (int t = wave0; t < NTASK; t += NWAVE) {
        size_t base = ((size_t)t << 8) | (size_t)lane;  // t*4 pixels * 64 float4
        float s[4], m[4];
#pragma unroll
        for (int i = 0; i < 4; ++i) {
            float4 v = x4[base + (size_t)i * 64];
            s[i] = (v.x + v.y) + (v.z + v.w);
            m[i] = fmaxf(fmaxf(v.x, v.y), fmaxf(v.z, v.w));
        }
#pragma unroll
        for (int o = 32; o > 0; o >>= 1) {
#pragma unroll
            for (int i = 0; i < 4; ++i) {
                s[i] += __shfl_down(s[i], o, 64);
                m[i] = fmaxf(m[i], __shfl_down(m[i], o, 64));
            }
        }
        if (lane == 0) {
            float4* p4 = (float4*)pooled;   // pooled as [NPIX][2] floats
            p4[t * 2]     = make_float4(s[0] * (1.0f / 256.0f), m[0],
                                        s[1] * (1.0f / 256.0f), m[1]);
            p4[t * 2 + 1] = make_float4(s[2] * (1.0f / 256.0f), m[2],
                                        s[3] * (1.0f / 256.0f), m[3]);
        }
    }

    cg::this_grid().sync();   // pooled fully written & visible device-wide

    // ---- Phase 2: conv + sigmoid + scale ----
    const float2* k2 = (const float2*)cw;   // [7,7,2,1] HWIO -> float2[49]
    float bias = cb[0];
    for (int t = wave0; t < NTASK; t += NWAVE) {
        size_t base = ((size_t)t << 8) | (size_t)lane;
        float4 v0 = x4[base];               // L3-hot after phase 1
        float4 v1 = x4[base + 64];
        float4 v2 = x4[base + 128];
        float4 v3 = x4[base + 192];

        int g   = lane >> 4;                // 16-lane group g -> pixel t*4+g
        int l   = lane & 15;
        int pix = t * 4 + g;
        int b   = pix / (HH * WW);
        int hw  = pix % (HH * WW);
        int h   = hw / WW;
        int w   = hw % WW;

        const float2* p2 = (const float2*)pooled + (size_t)b * HH * WW;
        float acc = 0.0f;
#pragma unroll
        for (int tp = 0; tp < 4; ++tp) {
            int tap = l + tp * 16;
            if (tap < 49) {
                int dh = tap / 7;
                int dw = tap - dh * 7;
                int ih = h + dh - 3;
                int iw = w + dw - 3;
                if (ih >= 0 && ih < HH && iw >= 0 && iw < WW) {
                    float2 p = p2[ih * WW + iw];
                    float2 k = k2[tap];
                    acc = fmaf(p.y, k.y, fmaf(p.x, k.x, acc));
                }
            }
        }
#pragma unroll
        for (int o = 8; o > 0; o >>= 1) acc += __shfl_xor(acc, o, 64);
        float a = 1.0f / (1.0f + expf(-(acc + bias)));

        float a0 = __shfl(a,  0, 64);
        float a1 = __shfl(a, 16, 64);
        float a2 = __shfl(a, 32, 64);
        float a3 = __shfl(a, 48, 64);

        float4* o4 = (float4*)out;
        v0.x *= a0; v0.y *= a0; v0.z *= a0; v0.w *= a0;
        v1.x *= a1; v1.y *= a1; v1.z *= a1; v1.w *= a1;
        v2.x *= a2; v2.y *= a2; v2.z *= a2; v2.w *= a2;
        v3.x *= a3; v3.y *= a3; v3.z *= a3; v3.w *= a3;
        o4[base]       = v0;
        o4[base + 64]  = v1;
        o4[base + 128] = v2;
        o4[base + 192] = v3;
    }
}

extern "C" void kernel_launch(void* const* d_in, const int* in_sizes, int n_in,
                              void* d_out, int out_size, void* d_ws, size_t ws_size,
                              hipStream_t stream) {
    const float* x  = (const float*)d_in[0];
    const float* cw = (const float*)d_in[1];   // [7,7,2,1] HWIO
    const float* cb = (const float*)d_in[2];   // [1]
    float* out = (float*)d_out;
    float* pooled = (float*)d_ws;              // NPIX*2 floats = 0.8 MB

    void* args[] = {(void*)&x, (void*)&cw, (void*)&cb, (void*)&out, (void*)&pooled};
    hipLaunchCooperativeKernel((void*)fused_all, dim3(NBLK), dim3(256),
                               args, 0, stream);
}

// Round 4
// 195.440 us; speedup vs baseline: 1.5128x; 1.5128x over previous
//
#include <hip/hip_runtime.h>
#include <math.h>

#define BB 32
#define HH 56
#define WW 56
#define CC 256
#define NPIX (BB * HH * WW)   // 100352 pixels; CC=256 floats per pixel

// Kernel 1: per-pixel channel mean + max.
// 4 pixels per wave (4 independent float4 loads in flight), 4 waves/block.
// 25088 one-task waves: CP retire-and-backfill gives max memory-level
// parallelism (round-3 coop/grid-stride variant proved 3x WORSE: 1.3 TB/s).
__global__ __launch_bounds__(256) void pool_kernel(const float* __restrict__ x,
                                                   float* __restrict__ pooled) {
    int wid  = blockIdx.x * 4 + (threadIdx.x >> 6);   // wave id, 4 pixels each
    int lane = threadIdx.x & 63;
    const float4* x4 = (const float4*)x;
    size_t base = ((size_t)wid << 8) | (size_t)lane;  // wid*4 pixels * 64 float4

    float s[4], m[4];
#pragma unroll
    for (int i = 0; i < 4; ++i) {
        float4 v = x4[base + (size_t)i * 64];
        s[i] = (v.x + v.y) + (v.z + v.w);
        m[i] = fmaxf(fmaxf(v.x, v.y), fmaxf(v.z, v.w));
    }
#pragma unroll
    for (int o = 32; o > 0; o >>= 1) {
#pragma unroll
        for (int i = 0; i < 4; ++i) {
            s[i] += __shfl_down(s[i], o, 64);
            m[i] = fmaxf(m[i], __shfl_down(m[i], o, 64));
        }
    }
    if (lane == 0) {
        float4* p4 = (float4*)pooled;   // pooled as [NPIX][2] floats
        p4[wid * 2]     = make_float4(s[0] * (1.0f / 256.0f), m[0],
                                      s[1] * (1.0f / 256.0f), m[1]);
        p4[wid * 2 + 1] = make_float4(s[2] * (1.0f / 256.0f), m[2],
                                      s[3] * (1.0f / 256.0f), m[3]);
    }
}

// Kernel 2: fused 7x7 'SAME' conv (2->1 ch) + bias + sigmoid + broadcast scale.
// 4 pixels per wave: 16-lane group g owns pixel (wid*4+g); each lane takes 4
// conv taps, 4-step shfl_xor butterfly within the group, 4 broadcasts, then
// each lane scales its 4 float4s of x (loads issued FIRST: L3-hot after k1 —
// round-3 counters proved the re-read is fully L3-absorbed, FETCH=103.5 MB).
__global__ __launch_bounds__(256) void fused_kernel(const float* __restrict__ x,
                                                    const float* __restrict__ pooled,
                                                    const float* __restrict__ cw,
                                                    const float* __restrict__ cb,
                                                    float* __restrict__ out) {
    int wid  = blockIdx.x * 4 + (threadIdx.x >> 6);
    int lane = threadIdx.x & 63;

    const float4* x4 = (const float4*)x;
    size_t base = ((size_t)wid << 8) | (size_t)lane;
    float4 v0 = x4[base];
    float4 v1 = x4[base + 64];
    float4 v2 = x4[base + 128];
    float4 v3 = x4[base + 192];

    int g   = lane >> 4;               // group 0..3 -> pixel wid*4+g
    int l   = lane & 15;               // lane in group
    int pix = wid * 4 + g;
    int b   = pix / (HH * WW);
    int hw  = pix % (HH * WW);
    int h   = hw / WW;
    int w   = hw % WW;

    const float2* p2 = (const float2*)pooled + (size_t)b * HH * WW;
    const float2* k2 = (const float2*)cw;   // [7,7,2,1] HWIO -> float2[49]
    float acc = 0.0f;
#pragma unroll
    for (int t = 0; t < 4; ++t) {
        int tap = l + t * 16;
        if (tap < 49) {
            int dh = tap / 7;
            int dw = tap - dh * 7;
            int ih = h + dh - 3;
            int iw = w + dw - 3;
            if (ih >= 0 && ih < HH && iw >= 0 && iw < WW) {
                float2 p = p2[ih * WW + iw];
                float2 k = k2[tap];
                acc = fmaf(p.y, k.y, fmaf(p.x, k.x, acc));
            }
        }
    }
#pragma unroll
    for (int o = 8; o > 0; o >>= 1) acc += __shfl_xor(acc, o, 64);
    float a = 1.0f / (1.0f + expf(-(acc + cb[0])));   // every lane has its group's a

    float a0 = __shfl(a,  0, 64);
    float a1 = __shfl(a, 16, 64);
    float a2 = __shfl(a, 32, 64);
    float a3 = __shfl(a, 48, 64);

    float4* o4 = (float4*)out;
    v0.x *= a0; v0.y *= a0; v0.z *= a0; v0.w *= a0;
    v1.x *= a1; v1.y *= a1; v1.z *= a1; v1.w *= a1;
    v2.x *= a2; v2.y *= a2; v2.z *= a2; v2.w *= a2;
    v3.x *= a3; v3.y *= a3; v3.z *= a3; v3.w *= a3;
    o4[base]       = v0;
    o4[base + 64]  = v1;
    o4[base + 128] = v2;
    o4[base + 192] = v3;
}

extern "C" void kernel_launch(void* const* d_in, const int* in_sizes, int n_in,
                              void* d_out, int out_size, void* d_ws, size_t ws_size,
                              hipStream_t stream) {
    const float* x  = (const float*)d_in[0];
    const float* cw = (const float*)d_in[1];   // [7,7,2,1] HWIO
    const float* cb = (const float*)d_in[2];   // [1]
    float* out = (float*)d_out;

    float* pooled = (float*)d_ws;              // NPIX*2 floats = 0.8 MB

    // 1) pool: 4 pixels/wave, 16 pixels/block -> 6272 blocks
    pool_kernel<<<NPIX / 16, 256, 0, stream>>>(x, pooled);
    // 2) conv+sigmoid+scale fused: 4 pixels/wave -> 6272 blocks
    fused_kernel<<<NPIX / 16, 256, 0, stream>>>(x, pooled, cw, cb, out);
}

// Round 6
// 193.257 us; speedup vs baseline: 1.5299x; 1.0113x over previous
//
#include <hip/hip_runtime.h>
#include <math.h>

#define BB 32
#define HH 56
#define WW 56
#define CC 256
#define NPIX (BB * HH * WW)   // 100352 pixels; CC=256 floats per pixel

typedef float f32x4 __attribute__((ext_vector_type(4)));  // clang-native vec4
                                                          // (nontemporal builtin
                                                          // rejects HIP float4)

// Kernel 1: per-pixel channel mean + max.
// 16-lane group per pixel (4 pixels/wave): each lane loads 4 float4s of its
// group's pixel (four contiguous 256B runs per step -> fully coalesced),
// reduces them THREAD-LOCALLY (pure VALU), then a 4-step shfl_xor butterfly
// within the group. 8 cross-lane ops/wave vs 48 in the round-1 version --
// cross-lane ops are ds-permute-class and sit on the dependent path.
__global__ __launch_bounds__(256) void pool_kernel(const float* __restrict__ x,
                                                   float* __restrict__ pooled) {
    int wid  = blockIdx.x * 4 + (threadIdx.x >> 6);   // wave id, 4 pixels each
    int lane = threadIdx.x & 63;
    int g    = lane >> 4;              // group 0..3 -> pixel wid*4+g
    int l    = lane & 15;              // lane in group
    const float4* x4 = (const float4*)x;

    // pixel (wid*4+g) spans float4 indices [(wid*4+g)*64, +64)
    size_t base = ((size_t)wid << 8) + (size_t)g * 64 + (size_t)l;
    float4 v0 = x4[base];
    float4 v1 = x4[base + 16];
    float4 v2 = x4[base + 32];
    float4 v3 = x4[base + 48];

    float s = ((v0.x + v0.y) + (v0.z + v0.w)) + ((v1.x + v1.y) + (v1.z + v1.w))
            + ((v2.x + v2.y) + (v2.z + v2.w)) + ((v3.x + v3.y) + (v3.z + v3.w));
    float m = fmaxf(fmaxf(fmaxf(fmaxf(v0.x, v0.y), fmaxf(v0.z, v0.w)),
                          fmaxf(fmaxf(v1.x, v1.y), fmaxf(v1.z, v1.w))),
                    fmaxf(fmaxf(fmaxf(v2.x, v2.y), fmaxf(v2.z, v2.w)),
                          fmaxf(fmaxf(v3.x, v3.y), fmaxf(v3.z, v3.w))));

#pragma unroll
    for (int o = 8; o > 0; o >>= 1) {         // butterfly stays inside 16-lane group
        s += __shfl_xor(s, o, 64);
        m = fmaxf(m, __shfl_xor(m, o, 64));
    }
    if (l == 0) {
        float2* p2 = (float2*)pooled;          // pooled as [NPIX]{mean,max}
        p2[wid * 4 + g] = make_float2(s * (1.0f / 256.0f), m);
    }
}

// Kernel 2: fused 7x7 'SAME' conv (2->1 ch) + bias + sigmoid + broadcast scale.
// 4 pixels per wave: 16-lane group g owns pixel (wid*4+g); each lane takes 4
// conv taps, 4-step shfl_xor butterfly within the group, 4 broadcasts, then
// each lane scales its 4 float4s of x (loads issued FIRST: L3-hot after k1 --
// round-3 counters proved the re-read is fully L3-absorbed, FETCH=103.5 MB).
// Out stores are NONTEMPORAL: out is write-once, keep L3 for x.
__global__ __launch_bounds__(256) void fused_kernel(const float* __restrict__ x,
                                                    const float* __restrict__ pooled,
                                                    const float* __restrict__ cw,
                                                    const float* __restrict__ cb,
                                                    float* __restrict__ out) {
    int wid  = blockIdx.x * 4 + (threadIdx.x >> 6);
    int lane = threadIdx.x & 63;

    const float4* x4 = (const float4*)x;
    size_t base = ((size_t)wid << 8) | (size_t)lane;
    float4 v0 = x4[base];
    float4 v1 = x4[base + 64];
    float4 v2 = x4[base + 128];
    float4 v3 = x4[base + 192];

    int g   = lane >> 4;               // group 0..3 -> pixel wid*4+g
    int l   = lane & 15;               // lane in group
    int pix = wid * 4 + g;
    int b   = pix / (HH * WW);
    int hw  = pix % (HH * WW);
    int h   = hw / WW;
    int w   = hw % WW;

    const float2* p2 = (const float2*)pooled + (size_t)b * HH * WW;
    const float2* k2 = (const float2*)cw;   // [7,7,2,1] HWIO -> float2[49]
    float acc = 0.0f;
#pragma unroll
    for (int t = 0; t < 4; ++t) {
        int tap = l + t * 16;
        if (tap < 49) {
            int dh = tap / 7;
            int dw = tap - dh * 7;
            int ih = h + dh - 3;
            int iw = w + dw - 3;
            if (ih >= 0 && ih < HH && iw >= 0 && iw < WW) {
                float2 p = p2[ih * WW + iw];
                float2 k = k2[tap];
                acc = fmaf(p.y, k.y, fmaf(p.x, k.x, acc));
            }
        }
    }
#pragma unroll
    for (int o = 8; o > 0; o >>= 1) acc += __shfl_xor(acc, o, 64);
    float a = 1.0f / (1.0f + expf(-(acc + cb[0])));   // every lane has its group's a

    float a0 = __shfl(a,  0, 64);
    float a1 = __shfl(a, 16, 64);
    float a2 = __shfl(a, 32, 64);
    float a3 = __shfl(a, 48, 64);

    f32x4* o4 = (f32x4*)out;
    f32x4 w0 = {v0.x * a0, v0.y * a0, v0.z * a0, v0.w * a0};
    f32x4 w1 = {v1.x * a1, v1.y * a1, v1.z * a1, v1.w * a1};
    f32x4 w2 = {v2.x * a2, v2.y * a2, v2.z * a2, v2.w * a2};
    f32x4 w3 = {v3.x * a3, v3.y * a3, v3.z * a3, v3.w * a3};
    __builtin_nontemporal_store(w0, &o4[base]);
    __builtin_nontemporal_store(w1, &o4[base + 64]);
    __builtin_nontemporal_store(w2, &o4[base + 128]);
    __builtin_nontemporal_store(w3, &o4[base + 192]);
}

extern "C" void kernel_launch(void* const* d_in, const int* in_sizes, int n_in,
                              void* d_out, int out_size, void* d_ws, size_t ws_size,
                              hipStream_t stream) {
    const float* x  = (const float*)d_in[0];
    const float* cw = (const float*)d_in[1];   // [7,7,2,1] HWIO
    const float* cb = (const float*)d_in[2];   // [1]
    float* out = (float*)d_out;

    float* pooled = (float*)d_ws;              // NPIX*2 floats = 0.8 MB

    // 1) pool: 4 pixels/wave, 16 pixels/block -> 6272 blocks
    pool_kernel<<<NPIX / 16, 256, 0, stream>>>(x, pooled);
    // 2) conv+sigmoid+scale fused: 4 pixels/wave -> 6272 blocks
    fused_kernel<<<NPIX / 16, 256, 0, stream>>>(x, pooled, cw, cb, out);
}